// Round 1
// baseline (281.345 us; speedup 1.0000x reference)
//
#include <hip/hip_runtime.h>
#include <stdint.h>

#define DM   1024
#define NH   16
#define DH   64
#define BATCH 2
#define SEQ  2048
#define MTOT (BATCH*SEQ)

typedef __bf16 bf16x8 __attribute__((ext_vector_type(8)));
typedef float  floatx4 __attribute__((ext_vector_type(4)));
typedef unsigned short ushort4v __attribute__((ext_vector_type(4)));

__device__ __forceinline__ unsigned short f2bf(float f){
    unsigned u = __builtin_bit_cast(unsigned, f);
    u += 0x7fffu + ((u >> 16) & 1u);
    return (unsigned short)(u >> 16);
}

__device__ __forceinline__ void gload_lds16(const void* g, void* l){
    __builtin_amdgcn_global_load_lds(
        (const __attribute__((address_space(1))) unsigned int*)g,
        (__attribute__((address_space(3))) unsigned int*)l, 16, 0, 0);
}

// ---------------------------------------------------------------- cvt fp32->bf16
__global__ __launch_bounds__(256)
void cvt_f32_bf16(const float* __restrict__ in, unsigned short* __restrict__ out, int n4){
    int i = blockIdx.x * 256 + threadIdx.x;
    if(i < n4){
        float4 v = ((const float4*)in)[i];
        ushort4v o;
        o[0] = f2bf(v.x); o[1] = f2bf(v.y); o[2] = f2bf(v.z); o[3] = f2bf(v.w);
        *(ushort4v*)&out[(size_t)i*4] = o;
    }
}

// ---------------------------------------------------------------- NT GEMM (m97 structure)
// MODE 0: fp32 flat [M][N]; MODE 1: bf16 [B][H][T][DH]; MODE 2: bf16 V^T [B][H][DH][T]
template<int MODE>
__global__ __launch_bounds__(256, 3)
void gemm_nt(const unsigned short* __restrict__ A,
             const unsigned short* __restrict__ Bw,
             void* __restrict__ OutP)
{
    __shared__ unsigned short As[128*32];
    __shared__ unsigned short Bs[128*32];
    const int tid  = threadIdx.x;
    const int w    = tid >> 6, lane = tid & 63, q = lane >> 4, cl = lane & 15;
    const int i0   = blockIdx.x * 128, n0 = blockIdx.y * 128;
    const int wm   = (w & 1) * 64, wn = (w >> 1) * 64;

    floatx4 acc[4][4];
    #pragma unroll
    for(int a=0;a<4;a++)
        #pragma unroll
        for(int b=0;b<4;b++) acc[a][b] = (floatx4)(0.0f);

    const int srow = lane >> 2;
    const int soff = (lane & 3) * 16;

    for(int k0 = 0; k0 < 1024; k0 += 32){
        __syncthreads();
        #pragma unroll
        for(int t=0;t<2;t++){
            const int ra = (w*2 + t) * 16;
            gload_lds16((const char*)A  + ((size_t)(i0 + ra + srow)*1024 + k0)*2 + soff,
                        (char*)&As[ra*32]);
            gload_lds16((const char*)Bw + ((size_t)(n0 + ra + srow)*1024 + k0)*2 + soff,
                        (char*)&Bs[ra*32]);
        }
        __syncthreads();

        bf16x8 af[4], bfr[4];
        #pragma unroll
        for(int mi=0;mi<4;mi++) af[mi]  = *(const bf16x8*)&As[(wm + mi*16 + cl)*32 + q*8];
        #pragma unroll
        for(int ni=0;ni<4;ni++) bfr[ni] = *(const bf16x8*)&Bs[(wn + ni*16 + cl)*32 + q*8];
        #pragma unroll
        for(int mi=0;mi<4;mi++)
            #pragma unroll
            for(int ni=0;ni<4;ni++)
                acc[mi][ni] = __builtin_amdgcn_mfma_f32_16x16x32_bf16(af[mi], bfr[ni], acc[mi][ni], 0, 0, 0);
    }

    if(MODE == 0){
        float* O = (float*)OutP;
        #pragma unroll
        for(int mi=0;mi<4;mi++)
            #pragma unroll
            for(int ni=0;ni<4;ni++){
                const int gi = i0 + wm + mi*16 + q*4;
                const int gn = n0 + wn + ni*16 + cl;
                #pragma unroll
                for(int r=0;r<4;r++) O[(size_t)(gi + r)*1024 + gn] = acc[mi][ni][r];
            }
    } else if(MODE == 1){
        unsigned short* O = (unsigned short*)OutP;
        #pragma unroll
        for(int mi=0;mi<4;mi++)
            #pragma unroll
            for(int ni=0;ni<4;ni++){
                const int gi = i0 + wm + mi*16 + q*4;
                const int gn = n0 + wn + ni*16 + cl;
                const int h = gn >> 6, d = gn & 63;
                #pragma unroll
                for(int r=0;r<4;r++){
                    const int i = gi + r, b = i >> 11, t = i & 2047;
                    O[(((size_t)(b*16 + h))*2048 + t)*64 + d] = f2bf(acc[mi][ni][r]);
                }
            }
    } else {
        unsigned short* O = (unsigned short*)OutP;
        #pragma unroll
        for(int mi=0;mi<4;mi++)
            #pragma unroll
            for(int ni=0;ni<4;ni++){
                const int gi = i0 + wm + mi*16 + q*4;
                const int gn = n0 + wn + ni*16 + cl;
                const int h = gn >> 6, d = gn & 63;
                const int b = gi >> 11, t = gi & 2047;
                ushort4v o;
                #pragma unroll
                for(int r=0;r<4;r++) o[r] = f2bf(acc[mi][ni][r]);
                *(ushort4v*)&O[(((size_t)(b*16 + h))*64 + d)*2048 + t] = o;
            }
    }
}

// ---------------------------------------------------------------- retention core
__global__ __launch_bounds__(256, 3)
void retention(const unsigned short* __restrict__ Q,
               const unsigned short* __restrict__ K,
               const unsigned short* __restrict__ VT,
               float* __restrict__ Y)
{
    __shared__ unsigned short Ks[64*72];     // padded stride 72 el = 144 B
    __shared__ unsigned short Vs[64*72];
    __shared__ unsigned short Ss[4][32*72];  // per-wave decayed S

    const int tid = threadIdx.x;
    const int w = tid >> 6, lane = tid & 63, q = lane >> 4, cl = lane & 15;
    const int bt = 15 - (int)blockIdx.x;     // heavy diagonal blocks first
    const int bh = blockIdx.y;
    const int h  = bh & 15;
    const int i0 = bt * 128;
    const int wm = w * 32;
    const float lg = log2f(1.0f - exp2f(-5.0f - (float)h));

    bf16x8 qf[2][2];
    #pragma unroll
    for(int mi=0;mi<2;mi++)
        #pragma unroll
        for(int kk=0;kk<2;kk++)
            qf[mi][kk] = *(const bf16x8*)(Q + ((size_t)bh*SEQ + i0 + wm + mi*16 + cl)*64 + kk*32 + q*8);

    floatx4 Yacc[2][4];
    #pragma unroll
    for(int a=0;a<2;a++)
        #pragma unroll
        for(int b=0;b<4;b++) Yacc[a][b] = (floatx4)(0.0f);

    const int srow = tid >> 2;   // 0..63
    const int part = tid & 3;
    const int jt_max = 2*bt + 1;

    for(int jt = 0; jt <= jt_max; jt++){
        const int j0 = jt * 64;
        __syncthreads();
        {
            const unsigned short* gk = K  + ((size_t)bh*SEQ + j0 + srow)*64;
            *(bf16x8*)&Ks[srow*72 + part*8]      = *(const bf16x8*)(gk + part*8);
            *(bf16x8*)&Ks[srow*72 + 32 + part*8] = *(const bf16x8*)(gk + 32 + part*8);
            const unsigned short* gv = VT + ((size_t)bh*64 + srow)*SEQ + j0;
            *(bf16x8*)&Vs[srow*72 + part*8]      = *(const bf16x8*)(gv + part*8);
            *(bf16x8*)&Vs[srow*72 + 32 + part*8] = *(const bf16x8*)(gv + 32 + part*8);
        }
        __syncthreads();

        floatx4 S[2][4];
        #pragma unroll
        for(int a=0;a<2;a++)
            #pragma unroll
            for(int b=0;b<4;b++) S[a][b] = (floatx4)(0.0f);
        #pragma unroll
        for(int kk=0;kk<2;kk++){
            #pragma unroll
            for(int ni=0;ni<4;ni++){
                bf16x8 bk = *(const bf16x8*)&Ks[(ni*16 + cl)*72 + kk*32 + q*8];
                S[0][ni] = __builtin_amdgcn_mfma_f32_16x16x32_bf16(qf[0][kk], bk, S[0][ni], 0,0,0);
                S[1][ni] = __builtin_amdgcn_mfma_f32_16x16x32_bf16(qf[1][kk], bk, S[1][ni], 0,0,0);
            }
        }

        #pragma unroll
        for(int mi=0;mi<2;mi++)
            #pragma unroll
            for(int ni=0;ni<4;ni++){
                const int irow = wm + mi*16 + q*4;
                const int jcol = j0 + ni*16 + cl;
                #pragma unroll
                for(int r=0;r<4;r++){
                    const int d = (i0 + irow + r) - jcol;
                    const float f = (d >= 0) ? exp2f((float)d * lg) * 0.125f : 0.0f;
                    Ss[w][(mi*16 + q*4 + r)*72 + ni*16 + cl] = f2bf(S[mi][ni][r] * f);
                }
            }
        asm volatile("s_waitcnt lgkmcnt(0)" ::: "memory");

        #pragma unroll
        for(int kk=0;kk<2;kk++){
            bf16x8 as0 = *(const bf16x8*)&Ss[w][( 0 + cl)*72 + kk*32 + q*8];
            bf16x8 as1 = *(const bf16x8*)&Ss[w][(16 + cl)*72 + kk*32 + q*8];
            #pragma unroll
            for(int nt=0;nt<4;nt++){
                bf16x8 bv = *(const bf16x8*)&Vs[(nt*16 + cl)*72 + kk*32 + q*8];
                Yacc[0][nt] = __builtin_amdgcn_mfma_f32_16x16x32_bf16(as0, bv, Yacc[0][nt], 0,0,0);
                Yacc[1][nt] = __builtin_amdgcn_mfma_f32_16x16x32_bf16(as1, bv, Yacc[1][nt], 0,0,0);
            }
        }
    }

    #pragma unroll
    for(int mi=0;mi<2;mi++)
        #pragma unroll
        for(int nt=0;nt<4;nt++){
            const int gi = i0 + wm + mi*16 + q*4;
            const int gd = nt*16 + cl;
            #pragma unroll
            for(int r=0;r<4;r++)
                Y[((size_t)bh*SEQ + gi + r)*64 + gd] = Yacc[mi][nt][r];
        }
}

// ---------------------------------------------------------------- GroupNorm
__global__ __launch_bounds__(256)
void gn_stats(const float* __restrict__ Y, float* __restrict__ st){
    const int g = blockIdx.x >> 3;
    const int s = blockIdx.x & 7;
    const float4* p = (const float4*)(Y + (size_t)g*131072 + (size_t)s*16384);
    float s1 = 0.f, s2 = 0.f;
    #pragma unroll
    for(int it=0; it<16; it++){
        float4 v = p[it*256 + threadIdx.x];
        s1 += v.x + v.y + v.z + v.w;
        s2 += v.x*v.x + v.y*v.y + v.z*v.z + v.w*v.w;
    }
    #pragma unroll
    for(int o=32;o>0;o>>=1){ s1 += __shfl_down(s1,o); s2 += __shfl_down(s2,o); }
    __shared__ float r1[4], r2[4];
    const int w = threadIdx.x >> 6, lane = threadIdx.x & 63;
    if(lane == 0){ r1[w] = s1; r2[w] = s2; }
    __syncthreads();
    if(threadIdx.x == 0){
        atomicAdd(&st[g*2+0], r1[0]+r1[1]+r1[2]+r1[3]);
        atomicAdd(&st[g*2+1], r2[0]+r2[1]+r2[2]+r2[3]);
    }
}

__global__ __launch_bounds__(256)
void gn_norm(const float* __restrict__ Y, const float* __restrict__ st,
             const float* __restrict__ gw, const float* __restrict__ gb,
             unsigned short* __restrict__ Out){
    const int e4 = blockIdx.x*256 + threadIdx.x;
    float4 v = ((const float4*)Y)[e4];
    const int e = e4 * 4;
    const int g = e >> 17;
    const int t = (e >> 6) & 2047;
    const int d = e & 63;
    const int h = g & 15, b = g >> 4;
    const float mean = st[g*2+0] * (1.0f/131072.0f);
    const float var  = st[g*2+1] * (1.0f/131072.0f) - mean*mean;
    const float inv  = rsqrtf(var + 1e-5f);
    const int c = h*64 + d;
    ushort4v o;
    o[0] = f2bf((v.x - mean)*inv*gw[c+0] + gb[c+0]);
    o[1] = f2bf((v.y - mean)*inv*gw[c+1] + gb[c+1]);
    o[2] = f2bf((v.z - mean)*inv*gw[c+2] + gb[c+2]);
    o[3] = f2bf((v.w - mean)*inv*gw[c+3] + gb[c+3]);
    *(ushort4v*)&Out[((size_t)(b*2048 + t))*1024 + c] = o;
}

// ---------------------------------------------------------------- launch
extern "C" void kernel_launch(void* const* d_in, const int* in_sizes, int n_in,
                              void* d_out, int out_size, void* d_ws, size_t ws_size,
                              hipStream_t stream){
    const float* x  = (const float*)d_in[0];
    const float* Wq = (const float*)d_in[1];
    const float* Wk = (const float*)d_in[2];
    const float* Wv = (const float*)d_in[3];
    const float* Wo = (const float*)d_in[4];
    const float* gw = (const float*)d_in[5];
    const float* gb = (const float*)d_in[6];

    char* ws = (char*)d_ws;
    unsigned short* xb  = (unsigned short*)(ws + ((size_t) 0<<20));
    unsigned short* wqb = (unsigned short*)(ws + ((size_t) 8<<20));
    unsigned short* wkb = (unsigned short*)(ws + ((size_t)10<<20));
    unsigned short* wvb = (unsigned short*)(ws + ((size_t)12<<20));
    unsigned short* wob = (unsigned short*)(ws + ((size_t)14<<20));
    unsigned short* qb  = (unsigned short*)(ws + ((size_t)16<<20));
    unsigned short* kb  = (unsigned short*)(ws + ((size_t)24<<20));
    unsigned short* vtb = (unsigned short*)(ws + ((size_t)32<<20));
    float*          yb  = (float*)         (ws + ((size_t)40<<20));
    unsigned short* ynb = (unsigned short*)(ws + ((size_t)56<<20));
    float*          st  = (float*)         (ws + ((size_t)64<<20));

    cvt_f32_bf16<<<4096, 256, 0, stream>>>(x,  xb,  1048576);
    cvt_f32_bf16<<<1024, 256, 0, stream>>>(Wq, wqb, 262144);
    cvt_f32_bf16<<<1024, 256, 0, stream>>>(Wk, wkb, 262144);
    cvt_f32_bf16<<<1024, 256, 0, stream>>>(Wv, wvb, 262144);
    cvt_f32_bf16<<<1024, 256, 0, stream>>>(Wo, wob, 262144);

    gemm_nt<1><<<dim3(32,8,1), 256, 0, stream>>>(xb, wqb, (void*)qb);
    gemm_nt<1><<<dim3(32,8,1), 256, 0, stream>>>(xb, wkb, (void*)kb);
    gemm_nt<2><<<dim3(32,8,1), 256, 0, stream>>>(xb, wvb, (void*)vtb);

    retention<<<dim3(16,32,1), 256, 0, stream>>>(qb, kb, vtb, yb);

    hipMemsetAsync(st, 0, 64*sizeof(float), stream);
    gn_stats<<<256, 256, 0, stream>>>(yb, st);
    gn_norm<<<8192, 256, 0, stream>>>(yb, st, gw, gb, ynb);

    gemm_nt<0><<<dim3(32,8,1), 256, 0, stream>>>(ynb, wob, d_out);
}

// Round 2
// 195.613 us; speedup vs baseline: 1.4383x; 1.4383x over previous
//
#include <hip/hip_runtime.h>
#include <stdint.h>

// MultiScaleRetention pipeline, R2.
// R2 changes vs R1: decay folded into Q/K scaling (GEMM epilogue), retention
// inner loop has no exp2; balanced 17-tile blocks via (x,15-x) pairing + j-split
// with compact Y1c partial; XOR-swizzled LDS + global_load_lds staging in
// retention; fused QKV GEMM (768 blocks); output GEMM 128x64 tiles (512 blocks);
// fixed gn_norm grid overrun (8192 -> 4096, was scribbling over st).
//
// ws layout (needs 64MB+256B, same as R1):
//  [0,8)  xb   (bf16 x)        -- dead after gemm_qkv; reused as Y1c (8MB)
//  [8,10) wqb  [10,12) wkb  [12,14) wvb   -- dead after gemm_qkv
//  [14,16) wob                  -- alive until gemm_out
//  [16,24) qb  [24,32) kb  [32,40) vtb (V^T [B,H,DH,T])
//  [40,56) Y0 fp32  [56,64) ynb bf16
//  [64MB) st (64 floats)

#define SEQ 2048

typedef __bf16 bf16x8 __attribute__((ext_vector_type(8)));
typedef float  floatx4 __attribute__((ext_vector_type(4)));
typedef unsigned short ushort4v __attribute__((ext_vector_type(4)));

__device__ __forceinline__ unsigned short f2bf(float f){
    unsigned u = __builtin_bit_cast(unsigned, f);
    u += 0x7fffu + ((u >> 16) & 1u);
    return (unsigned short)(u >> 16);
}

__device__ __forceinline__ void gload_lds16(const void* g, void* l){
    __builtin_amdgcn_global_load_lds(
        (const __attribute__((address_space(1))) unsigned int*)g,
        (__attribute__((address_space(3))) unsigned int*)l, 16, 0, 0);
}

// ---------------------------------------------------------------- cvt x
__global__ __launch_bounds__(256)
void cvt_f32_bf16(const float* __restrict__ in, unsigned short* __restrict__ out, int n4){
    int i = blockIdx.x * 256 + threadIdx.x;
    if(i < n4){
        float4 v = ((const float4*)in)[i];
        ushort4v o;
        o[0] = f2bf(v.x); o[1] = f2bf(v.y); o[2] = f2bf(v.z); o[3] = f2bf(v.w);
        *(ushort4v*)&out[(size_t)i*4] = o;
    }
}

// ---------------------------------------------------------------- cvt all 4 weights
__global__ __launch_bounds__(256)
void cvt_w4(const float* __restrict__ w0, const float* __restrict__ w1,
            const float* __restrict__ w2, const float* __restrict__ w3,
            unsigned short* __restrict__ o0, unsigned short* __restrict__ o1,
            unsigned short* __restrict__ o2, unsigned short* __restrict__ o3){
    const int blk = blockIdx.x, seg = blk >> 10;
    const int i = (blk & 1023)*256 + threadIdx.x;
    const float* src = (seg==0)?w0:(seg==1)?w1:(seg==2)?w2:w3;
    unsigned short* dst = (seg==0)?o0:(seg==1)?o1:(seg==2)?o2:o3;
    float4 v = ((const float4*)src)[i];
    ushort4v o;
    o[0] = f2bf(v.x); o[1] = f2bf(v.y); o[2] = f2bf(v.z); o[3] = f2bf(v.w);
    *(ushort4v*)&dst[(size_t)i*4] = o;
}

// ---------------------------------------------------------------- fused QKV GEMM
// grid (32, 24): y<8 -> Q (scale 0.125*gamma^t), y<16 -> K (scale gamma^-t),
// else V^T store. A = x bf16 [4096,1024], W row-major [1024,1024] (NT).
__global__ __launch_bounds__(256, 3)
void gemm_qkv(const unsigned short* __restrict__ A,
              const unsigned short* __restrict__ Wq,
              const unsigned short* __restrict__ Wk,
              const unsigned short* __restrict__ Wv,
              unsigned short* __restrict__ Qo,
              unsigned short* __restrict__ Ko,
              unsigned short* __restrict__ Vo)
{
    __shared__ unsigned short As[128*32];
    __shared__ unsigned short Bs[128*32];
    const int tid  = threadIdx.x;
    const int w    = tid >> 6, lane = tid & 63, q = lane >> 4, cl = lane & 15;
    const int i0   = blockIdx.x * 128;
    const int ysel = blockIdx.y;
    int mode, n0;
    const unsigned short* Bw;
    unsigned short* O;
    if(ysel < 8)      { mode = 0; Bw = Wq; O = Qo; n0 = ysel*128; }
    else if(ysel < 16){ mode = 1; Bw = Wk; O = Ko; n0 = (ysel-8)*128; }
    else              { mode = 2; Bw = Wv; O = Vo; n0 = (ysel-16)*128; }
    const int wm = (w & 1) * 64, wn = (w >> 1) * 64;

    floatx4 acc[4][4];
    #pragma unroll
    for(int a=0;a<4;a++)
        #pragma unroll
        for(int b=0;b<4;b++) acc[a][b] = (floatx4)(0.0f);

    const int srow = lane >> 2;
    const int soff = (lane & 3) * 16;

    for(int k0 = 0; k0 < 1024; k0 += 32){
        __syncthreads();
        #pragma unroll
        for(int t=0;t<2;t++){
            const int ra = (w*2 + t) * 16;
            gload_lds16((const char*)A  + ((size_t)(i0 + ra + srow)*1024 + k0)*2 + soff,
                        (char*)&As[ra*32]);
            gload_lds16((const char*)Bw + ((size_t)(n0 + ra + srow)*1024 + k0)*2 + soff,
                        (char*)&Bs[ra*32]);
        }
        __syncthreads();

        bf16x8 af[4], bfr[4];
        #pragma unroll
        for(int mi=0;mi<4;mi++) af[mi]  = *(const bf16x8*)&As[(wm + mi*16 + cl)*32 + q*8];
        #pragma unroll
        for(int ni=0;ni<4;ni++) bfr[ni] = *(const bf16x8*)&Bs[(wn + ni*16 + cl)*32 + q*8];
        #pragma unroll
        for(int mi=0;mi<4;mi++)
            #pragma unroll
            for(int ni=0;ni<4;ni++)
                acc[mi][ni] = __builtin_amdgcn_mfma_f32_16x16x32_bf16(af[mi], bfr[ni], acc[mi][ni], 0, 0, 0);
    }

    #pragma unroll
    for(int mi=0;mi<4;mi++)
        #pragma unroll
        for(int ni=0;ni<4;ni++){
            const int gi = i0 + wm + mi*16 + q*4;
            const int gn = n0 + wn + ni*16 + cl;
            const int h = gn >> 6, d = gn & 63;
            const float lgh = log2f(1.0f - exp2f(-5.0f - (float)h));
            if(mode == 2){
                const int b = gi >> 11, t = gi & 2047;
                ushort4v o;
                #pragma unroll
                for(int r=0;r<4;r++) o[r] = f2bf(acc[mi][ni][r]);
                *(ushort4v*)&Vo[(((size_t)(b*16 + h))*64 + d)*2048 + t] = o;
            } else {
                #pragma unroll
                for(int r=0;r<4;r++){
                    const int i = gi + r, b = i >> 11, t = i & 2047;
                    const float sc = (mode == 0) ? exp2f((float)t * lgh) * 0.125f
                                                 : exp2f(-(float)t * lgh);
                    O[(((size_t)(b*16 + h))*2048 + t)*64 + d] = f2bf(acc[mi][ni][r] * sc);
                }
            }
        }
}

// ---------------------------------------------------------------- retention core
// Decay pre-folded into Q/K. grid (16, 32): bx = s*8+x; pair (x, 15-x) split
// into two uniform 17-j-tile blocks. s=0 -> Y0 (full tile x + partial 15-x),
// s=1 -> compact Y1c [bh][t-1024][d] (rows >= 1024 only).
// LDS XOR-swizzled in 16B chunks: elem(r,c) at r*64 + (((c>>3)^(r&7))<<3)+(c&7).
__global__ __launch_bounds__(256, 2)
void retention(const unsigned short* __restrict__ Q,
               const unsigned short* __restrict__ K,
               const unsigned short* __restrict__ VT,
               float* __restrict__ Y0, float* __restrict__ Y1)
{
    __shared__ unsigned short Ks[64*64];
    __shared__ unsigned short Vs[64*64];
    __shared__ unsigned short Ss[4][32*64];

    const int tid = threadIdx.x;
    const int w = tid >> 6, lane = tid & 63, q = lane >> 4, cl = lane & 15;
    const int s = blockIdx.x >> 3, x = blockIdx.x & 7;
    const int bh = blockIdx.y;
    const int wm = w * 32;
    const int l3 = lane >> 3, l7 = lane & 7;
    const int c8 = l7 ^ l3;                 // staging column chunk (swizzle)
    const int cl7 = cl & 7;

    int segbt[2], segjb[2], segje[2], nseg;
    if(s == 0){ nseg = 2;
        segbt[0] = x;     segjb[0] = 0;      segje[0] = 2*x + 2;
        segbt[1] = 15-x;  segjb[1] = 0;      segje[1] = 15 - 2*x;
    } else { nseg = 1;
        segbt[0] = 15-x;  segjb[0] = 15-2*x; segje[0] = 32 - 2*x;
    }

    for(int seg = 0; seg < nseg; seg++){
        const int bt = segbt[seg], jb = segjb[seg], je = segje[seg];
        const int i0 = bt * 128;

        bf16x8 qf[2][2];
        #pragma unroll
        for(int mi=0;mi<2;mi++)
            #pragma unroll
            for(int kk=0;kk<2;kk++)
                qf[mi][kk] = *(const bf16x8*)(Q + ((size_t)bh*SEQ + i0 + wm + mi*16 + cl)*64 + kk*32 + q*8);

        floatx4 Yacc[2][4];
        #pragma unroll
        for(int a=0;a<2;a++)
            #pragma unroll
            for(int b=0;b<4;b++) Yacc[a][b] = (floatx4)(0.0f);

        for(int jt = jb; jt < je; jt++){
            const int j0 = jt * 64;
            __syncthreads();
            #pragma unroll
            for(int t=0;t<2;t++){
                const int r = w*16 + t*8 + l3;
                gload_lds16((const char*)K  + (((size_t)bh*SEQ + j0 + r)*64 + c8*8)*2,
                            (char*)&Ks[(w*16 + t*8)*64]);
                gload_lds16((const char*)VT + (((size_t)bh*64 + r)*SEQ + j0 + c8*8)*2,
                            (char*)&Vs[(w*16 + t*8)*64]);
            }
            __syncthreads();

            floatx4 S[2][4];
            #pragma unroll
            for(int a=0;a<2;a++)
                #pragma unroll
                for(int b=0;b<4;b++) S[a][b] = (floatx4)(0.0f);
            #pragma unroll
            for(int kk=0;kk<2;kk++){
                #pragma unroll
                for(int ni=0;ni<4;ni++){
                    bf16x8 bk = *(const bf16x8*)&Ks[(ni*16 + cl)*64 + (((kk*4+q) ^ cl7))*8];
                    S[0][ni] = __builtin_amdgcn_mfma_f32_16x16x32_bf16(qf[0][kk], bk, S[0][ni], 0,0,0);
                    S[1][ni] = __builtin_amdgcn_mfma_f32_16x16x32_bf16(qf[1][kk], bk, S[1][ni], 0,0,0);
                }
            }

            // mask (diagonal tiles only) + bf16 store to per-wave swizzled Ss
            const bool need_mask = (jt >= 2*bt);
            unsigned short* SsW = Ss[w];
            #pragma unroll
            for(int mi=0;mi<2;mi++)
                #pragma unroll
                for(int ni=0;ni<4;ni++)
                    #pragma unroll
                    for(int r=0;r<4;r++){
                        const int row = mi*16 + q*4 + r;
                        float v = S[mi][ni][r];
                        if(need_mask){
                            const int ii = i0 + wm + row;
                            const int jj = j0 + ni*16 + cl;
                            if(ii < jj) v = 0.0f;
                        }
                        SsW[row*64 + (((ni*2 + (cl>>3)) ^ (row & 7))*8) + cl7] = f2bf(v);
                    }
            asm volatile("s_waitcnt lgkmcnt(0)" ::: "memory");  // per-wave region

            #pragma unroll
            for(int kk=0;kk<2;kk++){
                const int ch = ((kk*4+q) ^ cl7)*8;
                bf16x8 as0 = *(const bf16x8*)&SsW[( 0 + cl)*64 + ch];
                bf16x8 as1 = *(const bf16x8*)&SsW[(16 + cl)*64 + ch];
                #pragma unroll
                for(int nt=0;nt<4;nt++){
                    bf16x8 bv = *(const bf16x8*)&Vs[(nt*16 + cl)*64 + ch];
                    Yacc[0][nt] = __builtin_amdgcn_mfma_f32_16x16x32_bf16(as0, bv, Yacc[0][nt], 0,0,0);
                    Yacc[1][nt] = __builtin_amdgcn_mfma_f32_16x16x32_bf16(as1, bv, Yacc[1][nt], 0,0,0);
                }
            }
        }

        // flush
        #pragma unroll
        for(int mi=0;mi<2;mi++)
            #pragma unroll
            for(int nt=0;nt<4;nt++){
                const int gi = i0 + wm + mi*16 + q*4;
                const int gd = nt*16 + cl;
                #pragma unroll
                for(int r=0;r<4;r++){
                    if(s == 0)
                        Y0[((size_t)bh*SEQ + gi + r)*64 + gd] = Yacc[mi][nt][r];
                    else
                        Y1[((size_t)bh*1024 + gi + r - 1024)*64 + gd] = Yacc[mi][nt][r];
                }
            }
    }
}

// ---------------------------------------------------------------- GroupNorm stats
// Y = Y0 (full) + Y1c (compact, rows t>=1024). 8 sub-blocks per group.
__global__ __launch_bounds__(256)
void gn_stats(const float* __restrict__ Y0, const float* __restrict__ Y1,
              float* __restrict__ st){
    const int g = blockIdx.x >> 3;
    const int s8 = blockIdx.x & 7;
    const float4* p0 = (const float4*)(Y0 + (size_t)g*131072 + (size_t)s8*16384);
    float s1 = 0.f, s2 = 0.f;
    #pragma unroll
    for(int it=0; it<16; it++){
        float4 v = p0[it*256 + threadIdx.x];
        s1 += v.x + v.y + v.z + v.w;
        s2 += v.x*v.x + v.y*v.y + v.z*v.z + v.w*v.w;
    }
    if(s8 >= 4){
        const float4* p1 = (const float4*)(Y1 + (size_t)g*65536 + (size_t)(s8-4)*16384);
        #pragma unroll
        for(int it=0; it<16; it++){
            float4 v0 = p0[it*256 + threadIdx.x];   // re-read for paired sum? no:
            (void)v0;
            float4 v = p1[it*256 + threadIdx.x];
            s1 += v.x + v.y + v.z + v.w;
            s2 += v.x*v.x + v.y*v.y + v.z*v.z + v.w*v.w;
        }
    }
    #pragma unroll
    for(int o=32;o>0;o>>=1){ s1 += __shfl_down(s1,o); s2 += __shfl_down(s2,o); }
    __shared__ float r1[4], r2[4];
    const int w = threadIdx.x >> 6, lane = threadIdx.x & 63;
    if(lane == 0){ r1[w] = s1; r2[w] = s2; }
    __syncthreads();
    if(threadIdx.x == 0){
        atomicAdd(&st[g*2+0], r1[0]+r1[1]+r1[2]+r1[3]);
        atomicAdd(&st[g*2+1], r2[0]+r2[1]+r2[2]+r2[3]);
    }
}

// NOTE on gn_stats sum-of-squares: var must be of (Y0+Y1), not Y0,Y1 separately.
// Handled by summing the COMBINED value where both exist -- see gn_stats2 below,
// which replaces gn_stats in the launch (kept gn_stats unreferenced-safe? no:
// we launch gn_stats2 only).
__global__ __launch_bounds__(256)
void gn_stats2(const float* __restrict__ Y0, const float* __restrict__ Y1,
               float* __restrict__ st){
    const int g = blockIdx.x >> 3;
    const int s8 = blockIdx.x & 7;
    const float4* p0 = (const float4*)(Y0 + (size_t)g*131072 + (size_t)s8*16384);
    const float4* p1 = (s8 >= 4) ? (const float4*)(Y1 + (size_t)g*65536 + (size_t)(s8-4)*16384) : nullptr;
    float s1 = 0.f, s2 = 0.f;
    #pragma unroll
    for(int it=0; it<16; it++){
        float4 v = p0[it*256 + threadIdx.x];
        if(p1){
            float4 u = p1[it*256 + threadIdx.x];
            v.x += u.x; v.y += u.y; v.z += u.z; v.w += u.w;
        }
        s1 += v.x + v.y + v.z + v.w;
        s2 += v.x*v.x + v.y*v.y + v.z*v.z + v.w*v.w;
    }
    #pragma unroll
    for(int o=32;o>0;o>>=1){ s1 += __shfl_down(s1,o); s2 += __shfl_down(s2,o); }
    __shared__ float r1[4], r2[4];
    const int w = threadIdx.x >> 6, lane = threadIdx.x & 63;
    if(lane == 0){ r1[w] = s1; r2[w] = s2; }
    __syncthreads();
    if(threadIdx.x == 0){
        atomicAdd(&st[g*2+0], r1[0]+r1[1]+r1[2]+r1[3]);
        atomicAdd(&st[g*2+1], r2[0]+r2[1]+r2[2]+r2[3]);
    }
}

// ---------------------------------------------------------------- GroupNorm apply
__global__ __launch_bounds__(256)
void gn_norm(const float* __restrict__ Y0, const float* __restrict__ Y1,
             const float* __restrict__ st,
             const float* __restrict__ gw, const float* __restrict__ gb,
             unsigned short* __restrict__ Out){
    const int e4 = blockIdx.x*256 + threadIdx.x;   // < 1048576
    float4 v = ((const float4*)Y0)[e4];
    const int e = e4 * 4;
    const int g = e >> 17;
    const int t = (e >> 6) & 2047;
    const int d = e & 63;
    if(t >= 1024){
        const size_t i1 = (((size_t)g*1024 + (t-1024))*64 + d) >> 2;
        float4 u = ((const float4*)Y1)[i1];
        v.x += u.x; v.y += u.y; v.z += u.z; v.w += u.w;
    }
    const int h = g & 15, b = g >> 4;
    const float mean = st[g*2+0] * (1.0f/131072.0f);
    const float var  = st[g*2+1] * (1.0f/131072.0f) - mean*mean;
    const float inv  = rsqrtf(var + 1e-5f);
    const int c = h*64 + d;
    ushort4v o;
    o[0] = f2bf((v.x - mean)*inv*gw[c+0] + gb[c+0]);
    o[1] = f2bf((v.y - mean)*inv*gw[c+1] + gb[c+1]);
    o[2] = f2bf((v.z - mean)*inv*gw[c+2] + gb[c+2]);
    o[3] = f2bf((v.w - mean)*inv*gw[c+3] + gb[c+3]);
    *(ushort4v*)&Out[((size_t)(b*2048 + t))*1024 + c] = o;
}

// ---------------------------------------------------------------- output GEMM
// C[4096,1024] fp32 = yn[4096,1024]bf16 * Wo^T. 128x64 tiles -> 512 blocks.
__global__ __launch_bounds__(256, 3)
void gemm_out(const unsigned short* __restrict__ A,
              const unsigned short* __restrict__ Bw,
              float* __restrict__ O)
{
    __shared__ unsigned short As[128*32];
    __shared__ unsigned short Bs[64*32];
    const int tid = threadIdx.x;
    const int w = tid >> 6, lane = tid & 63, q = lane >> 4, cl = lane & 15;
    const int i0 = blockIdx.x * 128, n0 = blockIdx.y * 64;
    const int wm = (w & 1) * 64, wn = (w >> 1) * 32;

    floatx4 acc[4][2];
    #pragma unroll
    for(int a=0;a<4;a++)
        #pragma unroll
        for(int b=0;b<2;b++) acc[a][b] = (floatx4)(0.0f);

    const int srow = lane >> 2;          // 0..15
    const int soff = (lane & 3) * 16;

    for(int k0 = 0; k0 < 1024; k0 += 32){
        __syncthreads();
        #pragma unroll
        for(int t=0;t<2;t++){
            const int ra = w*32 + t*16;
            gload_lds16((const char*)A + ((size_t)(i0 + ra + srow)*1024 + k0)*2 + soff,
                        (char*)&As[ra*32]);
        }
        gload_lds16((const char*)Bw + ((size_t)(n0 + w*16 + srow)*1024 + k0)*2 + soff,
                    (char*)&Bs[(w*16)*32]);
        __syncthreads();

        bf16x8 af[4], bfr[2];
        #pragma unroll
        for(int mi=0;mi<4;mi++) af[mi]  = *(const bf16x8*)&As[(wm + mi*16 + cl)*32 + q*8];
        #pragma unroll
        for(int ni=0;ni<2;ni++) bfr[ni] = *(const bf16x8*)&Bs[(wn + ni*16 + cl)*32 + q*8];
        #pragma unroll
        for(int mi=0;mi<4;mi++)
            #pragma unroll
            for(int ni=0;ni<2;ni++)
                acc[mi][ni] = __builtin_amdgcn_mfma_f32_16x16x32_bf16(af[mi], bfr[ni], acc[mi][ni], 0, 0, 0);
    }

    #pragma unroll
    for(int mi=0;mi<4;mi++)
        #pragma unroll
        for(int ni=0;ni<2;ni++){
            const int gi = i0 + wm + mi*16 + q*4;
            const int gn = n0 + wn + ni*16 + cl;
            #pragma unroll
            for(int r=0;r<4;r++) O[(size_t)(gi + r)*1024 + gn] = acc[mi][ni][r];
        }
}

// ---------------------------------------------------------------- launch
extern "C" void kernel_launch(void* const* d_in, const int* in_sizes, int n_in,
                              void* d_out, int out_size, void* d_ws, size_t ws_size,
                              hipStream_t stream){
    const float* x  = (const float*)d_in[0];
    const float* Wq = (const float*)d_in[1];
    const float* Wk = (const float*)d_in[2];
    const float* Wv = (const float*)d_in[3];
    const float* Wo = (const float*)d_in[4];
    const float* gw = (const float*)d_in[5];
    const float* gb = (const float*)d_in[6];

    char* ws = (char*)d_ws;
    unsigned short* xb  = (unsigned short*)(ws + ((size_t) 0<<20));  // 8 MB, reused as Y1c
    unsigned short* wqb = (unsigned short*)(ws + ((size_t) 8<<20));
    unsigned short* wkb = (unsigned short*)(ws + ((size_t)10<<20));
    unsigned short* wvb = (unsigned short*)(ws + ((size_t)12<<20));
    unsigned short* wob = (unsigned short*)(ws + ((size_t)14<<20));
    unsigned short* qb  = (unsigned short*)(ws + ((size_t)16<<20));
    unsigned short* kb  = (unsigned short*)(ws + ((size_t)24<<20));
    unsigned short* vtb = (unsigned short*)(ws + ((size_t)32<<20));
    float*          y0  = (float*)         (ws + ((size_t)40<<20));  // 16 MB
    unsigned short* ynb = (unsigned short*)(ws + ((size_t)56<<20));  // 8 MB
    float*          y1  = (float*)         (ws + ((size_t) 0<<20));  // 8 MB (over xb)
    float*          st  = (float*)         (ws + ((size_t)64<<20));  // 256 B

    cvt_f32_bf16<<<4096, 256, 0, stream>>>(x, xb, 1048576);
    cvt_w4<<<4096, 256, 0, stream>>>(Wq, Wk, Wv, Wo, wqb, wkb, wvb, wob);

    gemm_qkv<<<dim3(32,24,1), 256, 0, stream>>>(xb, wqb, wkb, wvb, qb, kb, vtb);

    retention<<<dim3(16,32,1), 256, 0, stream>>>(qb, kb, vtb, y0, y1);

    hipMemsetAsync(st, 0, 64*sizeof(float), stream);
    gn_stats2<<<256, 256, 0, stream>>>(y0, y1, st);
    gn_norm<<<4096, 256, 0, stream>>>(y0, y1, st, gw, gb, ynb);

    gemm_out<<<dim3(32,16,1), 256, 0, stream>>>(ynb, wob, (float*)d_out);
}

// Round 5
// 188.686 us; speedup vs baseline: 1.4911x; 1.0367x over previous
//
#include <hip/hip_runtime.h>
#include <stdint.h>

// MultiScaleRetention pipeline, R5 = R4 + V^T epilogue batch-offset fix.
// R3/R4 bug: gemm_qkv mode-2 (V^T) store used global token base i0 instead of
// within-batch (i0 & 2047); since b = i0>>11, the address was off by b*2048
// elements = exactly one d-row for batch 1 -> batch-1 V shifted by one channel
// -> deterministic absmax 9.9 (identical across R3/R4). Q/K epilogue already
// masked (tt & 2047), which is why only V was corrupted.
//
// ws layout: [0,8) xb (reused as Y1 fp32 [bh][64d][1024t] after gemm_qkv)
// [8,10) wqb [10,12) wkb [12,14) wvb [14,16) wob
// [16,24) qb [B,H,T,DH] bf16   [24,32) kb same   [32,40) vtb [B,H,DH,T] bf16
// [40,56) Y0 fp32 [bh][64d][2048t]   [56,64) ynb bf16 [t][c]
// [64MB) st (128 floats)

#define SEQ 2048

typedef __bf16 bf16x8 __attribute__((ext_vector_type(8)));
typedef float  floatx4 __attribute__((ext_vector_type(4)));
typedef unsigned short ushort4v __attribute__((ext_vector_type(4)));

__device__ __forceinline__ unsigned short f2bf(float f){
    __bf16 h = (__bf16)f;
    return __builtin_bit_cast(unsigned short, h);
}

__device__ __forceinline__ void gload_lds16(const void* g, void* l){
    __builtin_amdgcn_global_load_lds(
        (const __attribute__((address_space(1))) unsigned int*)g,
        (__attribute__((address_space(3))) unsigned int*)l, 16, 0, 0);
}

// ---------------------------------------------------------------- fused cvt + st zero
__global__ __launch_bounds__(256)
void cvt_all(const float* __restrict__ x,
             const float* __restrict__ w0, const float* __restrict__ w1,
             const float* __restrict__ w2, const float* __restrict__ w3,
             unsigned short* __restrict__ xb,
             unsigned short* __restrict__ o0, unsigned short* __restrict__ o1,
             unsigned short* __restrict__ o2, unsigned short* __restrict__ o3,
             float* __restrict__ st){
    const int blk = blockIdx.x;
    if(blk == 0 && threadIdx.x < 128) st[threadIdx.x] = 0.0f;
    const float* src; unsigned short* dst; size_t i;
    if(blk < 4096){ src = x; dst = xb; i = (size_t)blk*256 + threadIdx.x; }
    else {
        const int seg = (blk - 4096) >> 10;
        src = seg==0?w0:seg==1?w1:seg==2?w2:w3;
        dst = seg==0?o0:seg==1?o1:seg==2?o2:o3;
        i = (size_t)((blk - 4096) & 1023)*256 + threadIdx.x;
    }
    float4 v = ((const float4*)src)[i];
    ushort4v o;
    o[0]=f2bf(v.x); o[1]=f2bf(v.y); o[2]=f2bf(v.z); o[3]=f2bf(v.w);
    *(ushort4v*)&dst[i*4] = o;
}

// ---------------------------------------------------------------- fused QKV GEMM
// grid (32,24): y<8 Q (scale 0.125*gamma^t), y<16 K (gamma^-t), else V^T.
// Epilogue: LDS transpose (reusing As/Bs 16KB) -> coalesced 16B stores.
__global__ __launch_bounds__(256, 3)
void gemm_qkv(const unsigned short* __restrict__ A,
              const unsigned short* __restrict__ Wq,
              const unsigned short* __restrict__ Wk,
              const unsigned short* __restrict__ Wv,
              unsigned short* __restrict__ Qo,
              unsigned short* __restrict__ Ko,
              unsigned short* __restrict__ Vo)
{
    __shared__ unsigned short smem[8192];         // As[4096]+Bs[4096]; epi tile 64x128
    unsigned short* As = smem;
    unsigned short* Bs = smem + 4096;
    const int tid  = threadIdx.x;
    const int w    = tid >> 6, lane = tid & 63, q = lane >> 4, cl = lane & 15;
    const int i0   = blockIdx.x * 128;
    const int ysel = blockIdx.y;
    int mode, n0;
    const unsigned short* Bw;
    unsigned short* O;
    if(ysel < 8)      { mode = 0; Bw = Wq; O = Qo; n0 = ysel*128; }
    else if(ysel < 16){ mode = 1; Bw = Wk; O = Ko; n0 = (ysel-8)*128; }
    else              { mode = 2; Bw = Wv; O = Vo; n0 = (ysel-16)*128; }
    const int wm = (w & 1) * 64, wn = (w >> 1) * 64;

    floatx4 acc[4][4];
    #pragma unroll
    for(int a=0;a<4;a++)
        #pragma unroll
        for(int b=0;b<4;b++) acc[a][b] = (floatx4)(0.0f);

    const int srow = lane >> 2;
    const int soff = (lane & 3) * 16;

    for(int k0 = 0; k0 < 1024; k0 += 32){
        __syncthreads();
        #pragma unroll
        for(int t=0;t<2;t++){
            const int ra = (w*2 + t) * 16;
            gload_lds16((const char*)A  + ((size_t)(i0 + ra + srow)*1024 + k0)*2 + soff,
                        (char*)&As[ra*32]);
            gload_lds16((const char*)Bw + ((size_t)(n0 + ra + srow)*1024 + k0)*2 + soff,
                        (char*)&Bs[ra*32]);
        }
        __syncthreads();

        bf16x8 af[4], bfr[4];
        #pragma unroll
        for(int mi=0;mi<4;mi++) af[mi]  = *(const bf16x8*)&As[(wm + mi*16 + cl)*32 + q*8];
        #pragma unroll
        for(int ni=0;ni<4;ni++) bfr[ni] = *(const bf16x8*)&Bs[(wn + ni*16 + cl)*32 + q*8];
        #pragma unroll
        for(int mi=0;mi<4;mi++)
            #pragma unroll
            for(int ni=0;ni<4;ni++)
                acc[mi][ni] = __builtin_amdgcn_mfma_f32_16x16x32_bf16(af[mi], bfr[ni], acc[mi][ni], 0, 0, 0);
    }

    const int b = i0 >> 11;
    if(mode < 2){
        // Q/K -> [bh][t][64d]. Two t-half passes; LDS tile [64t][128d] swizzled.
        for(int p=0;p<2;p++){
            __syncthreads();
            if((w & 1) == p){
                #pragma unroll
                for(int ni=0;ni<4;ni++){
                    const int h = (n0 + wn + ni*16) >> 6;
                    const float lgh = log2f(1.0f - exp2f(-5.0f - (float)h));
                    const int d = wn + ni*16 + cl, d8 = d >> 3, d7 = d & 7;
                    #pragma unroll
                    for(int mi=0;mi<4;mi++)
                        #pragma unroll
                        for(int r=0;r<4;r++){
                            const int trow = mi*16 + q*4 + r;
                            const int tt = (i0 + p*64 + trow) & 2047;
                            const float sc = (mode==0) ? exp2f((float)tt*lgh)*0.125f
                                                       : exp2f(-(float)tt*lgh);
                            smem[trow*128 + ((d8 ^ (trow & 7))*8) + d7] = f2bf(acc[mi][ni][r]*sc);
                        }
                }
            }
            __syncthreads();
            const int trow = tid >> 2, part = tid & 3;
            const int tt = (i0 + p*64 + trow) & 2047;
            #pragma unroll
            for(int k=0;k<4;k++){
                const int c = k*4 + part;
                bf16x8 vrow = *(const bf16x8*)&smem[trow*128 + ((c ^ (trow & 7))*8)];
                const int h = (n0 + c*8) >> 6, dd = (c*8) & 63;
                *(bf16x8*)&O[(((size_t)(b*16 + h))*2048 + tt)*64 + dd] = vrow;
            }
        }
    } else {
        // V -> V^T [bh][d][2048t]. Two d-half passes; LDS tile [64d][128t].
        for(int p=0;p<2;p++){
            __syncthreads();
            if((w >> 1) == p){
                #pragma unroll
                for(int ni=0;ni<4;ni++){
                    const int drow = ni*16 + cl, dr7 = drow & 7;
                    #pragma unroll
                    for(int mi=0;mi<4;mi++){
                        const int t = wm + mi*16 + q*4;
                        const int c = (t >> 3) ^ dr7;
                        ushort4v pk;
                        #pragma unroll
                        for(int r=0;r<4;r++) pk[r] = f2bf(acc[mi][ni][r]);
                        *(ushort4v*)&smem[drow*128 + c*8 + (t & 7)] = pk;
                    }
                }
            }
            __syncthreads();
            const int drow = tid >> 2, part = tid & 3;
            const int dg = n0 + p*64 + drow;
            const int h = dg >> 6, dd = dg & 63;
            const int tbase = i0 & 2047;          // FIX: within-batch token base
            #pragma unroll
            for(int k=0;k<4;k++){
                const int c = k*4 + part;
                bf16x8 vrow = *(const bf16x8*)&smem[drow*128 + ((c ^ (drow & 7))*8)];
                *(bf16x8*)&O[(((size_t)(b*16 + h))*64 + dd)*2048 + tbase + c*8] = vrow;
            }
        }
    }
}

// ---------------------------------------------------------------- retention core
// S^T = K*Q^T (C-layout gives lane 4 consecutive j at fixed i -> b64 Ss writes,
// b128 Ss reads). Y^T = V^T*S^T, written [bh][d][t] coalesced.
__global__ __launch_bounds__(256, 2)
void retention(const unsigned short* __restrict__ Q,
               const unsigned short* __restrict__ K,
               const unsigned short* __restrict__ VT,
               float* __restrict__ Y0, float* __restrict__ Y1)
{
    __shared__ unsigned short Ks[64*64];
    __shared__ unsigned short Vs[64*64];
    __shared__ unsigned short Ss[4][32*64];

    const int tid = threadIdx.x;
    const int w = tid >> 6, lane = tid & 63, q = lane >> 4, cl = lane & 15;
    const int s = blockIdx.x >> 3, x = blockIdx.x & 7;
    const int bh = blockIdx.y;
    const int wm = w * 32;
    const int l3 = lane >> 3, l7 = lane & 7;
    const int c8 = l7 ^ l3;
    const int cl7 = cl & 7;

    int segbt[2], segjb[2], segje[2], nseg;
    if(s == 0){ nseg = 2;
        segbt[0] = x;     segjb[0] = 0;      segje[0] = 2*x + 2;
        segbt[1] = 15-x;  segjb[1] = 0;      segje[1] = 15 - 2*x;
    } else { nseg = 1;
        segbt[0] = 15-x;  segjb[0] = 15-2*x; segje[0] = 32 - 2*x;
    }

    for(int seg = 0; seg < nseg; seg++){
        const int bt = segbt[seg], jb = segjb[seg], je = segje[seg];
        const int i0 = bt * 128;

        bf16x8 qf[2][2];
        #pragma unroll
        for(int mi=0;mi<2;mi++)
            #pragma unroll
            for(int kk=0;kk<2;kk++)
                qf[mi][kk] = *(const bf16x8*)(Q + ((size_t)bh*SEQ + i0 + wm + mi*16 + cl)*64 + kk*32 + q*8);

        floatx4 Yacc[2][4];
        #pragma unroll
        for(int a=0;a<2;a++)
            #pragma unroll
            for(int b=0;b<4;b++) Yacc[a][b] = (floatx4)(0.0f);

        for(int jt = jb; jt < je; jt++){
            const int j0 = jt * 64;
            __syncthreads();
            #pragma unroll
            for(int t=0;t<2;t++){
                const int r = w*16 + t*8 + l3;
                gload_lds16((const char*)K  + (((size_t)bh*SEQ + j0 + r)*64 + c8*8)*2,
                            (char*)&Ks[(w*16 + t*8)*64]);
                gload_lds16((const char*)VT + (((size_t)bh*64 + r)*SEQ + j0 + c8*8)*2,
                            (char*)&Vs[(w*16 + t*8)*64]);
            }
            __syncthreads();

            // S^T[j][i] = K*Q^T : A-frag = K rows (m=j), B-frag = Q rows (n=i)
            floatx4 St[2][4];
            #pragma unroll
            for(int a=0;a<2;a++)
                #pragma unroll
                for(int b=0;b<4;b++) St[a][b] = (floatx4)(0.0f);
            #pragma unroll
            for(int kk=0;kk<2;kk++){
                #pragma unroll
                for(int ni=0;ni<4;ni++){
                    bf16x8 ak = *(const bf16x8*)&Ks[(ni*16 + cl)*64 + ((kk*4+q) ^ cl7)*8];
                    St[0][ni] = __builtin_amdgcn_mfma_f32_16x16x32_bf16(ak, qf[0][kk], St[0][ni], 0,0,0);
                    St[1][ni] = __builtin_amdgcn_mfma_f32_16x16x32_bf16(ak, qf[1][kk], St[1][ni], 0,0,0);
                }
            }

            // mask + pack; lane holds (i = wm+mi*16+cl, j = j0+ni*16+q*4+{0..3})
            const bool need_mask = (jt >= 2*bt);
            unsigned short* SsW = Ss[w];
            #pragma unroll
            for(int mi=0;mi<2;mi++){
                const int row = mi*16 + cl;
                const int sw = row & 7;
                const int ig = i0 + wm + row;
                #pragma unroll
                for(int ni=0;ni<4;ni++){
                    ushort4v pk;
                    #pragma unroll
                    for(int r=0;r<4;r++){
                        float v = St[mi][ni][r];
                        if(need_mask){
                            const int jg = j0 + ni*16 + q*4 + r;
                            if(ig < jg) v = 0.0f;
                        }
                        pk[r] = f2bf(v);
                    }
                    *(ushort4v*)&SsW[row*64 + (((ni*2 + (q>>1)) ^ sw)*8) + (q&1)*4] = pk;
                }
            }
            asm volatile("s_waitcnt lgkmcnt(0)" ::: "memory");  // per-wave region

            // Y^T += V^T * S^T : A-frag = V^T rows (m=d), B-frag = S^T (n=i)
            #pragma unroll
            for(int kk=0;kk<2;kk++){
                const int ch = ((kk*4+q) ^ cl7)*8;
                bf16x8 bs0 = *(const bf16x8*)&SsW[( 0 + cl)*64 + ch];
                bf16x8 bs1 = *(const bf16x8*)&SsW[(16 + cl)*64 + ch];
                #pragma unroll
                for(int nt=0;nt<4;nt++){
                    bf16x8 av = *(const bf16x8*)&Vs[(nt*16 + cl)*64 + ch];
                    Yacc[0][nt] = __builtin_amdgcn_mfma_f32_16x16x32_bf16(av, bs0, Yacc[0][nt], 0,0,0);
                    Yacc[1][nt] = __builtin_amdgcn_mfma_f32_16x16x32_bf16(av, bs1, Yacc[1][nt], 0,0,0);
                }
            }
        }

        // flush Y^T: (d = nt*16+q*4+r, i = i0+wm+mi*16+cl) -> coalesced in t
        #pragma unroll
        for(int mi=0;mi<2;mi++)
            #pragma unroll
            for(int nt=0;nt<4;nt++){
                const int ig = i0 + wm + mi*16 + cl;
                #pragma unroll
                for(int r=0;r<4;r++){
                    const int d = nt*16 + q*4 + r;
                    if(s == 0)
                        Y0[((size_t)bh*64 + d)*2048 + ig] = Yacc[mi][nt][r];
                    else
                        Y1[((size_t)bh*64 + d)*1024 + ig - 1024] = Yacc[mi][nt][r];
                }
            }
    }
}

// ---------------------------------------------------------------- GroupNorm stats
// Y0 [bh][64d][2048t] + Y1 compact [bh][64d][1024t] (t>=1024). grid = 32*8 = 256.
__global__ __launch_bounds__(256)
void gn_stats(const float* __restrict__ Y0, const float* __restrict__ Y1,
              float* __restrict__ st){
    const int g = blockIdx.x >> 3, s8 = blockIdx.x & 7;
    if(g >= 32) return;
    float s1 = 0.f, s2 = 0.f;
    #pragma unroll
    for(int it=0; it<16; it++){
        const int idx = it*256 + threadIdx.x;
        const int dl = idx >> 9;
        const int t4 = idx & 511;
        const int drow = g*64 + s8*8 + dl;
        float4 v = ((const float4*)Y0)[(size_t)drow*512 + t4];
        if(t4 >= 256){
            float4 u = ((const float4*)Y1)[(size_t)drow*256 + t4 - 256];
            v.x += u.x; v.y += u.y; v.z += u.z; v.w += u.w;
        }
        s1 += v.x + v.y + v.z + v.w;
        s2 += v.x*v.x + v.y*v.y + v.z*v.z + v.w*v.w;
    }
    #pragma unroll
    for(int o=32;o>0;o>>=1){ s1 += __shfl_down(s1,o); s2 += __shfl_down(s2,o); }
    __shared__ float r1[4], r2[4];
    const int w = threadIdx.x >> 6, lane = threadIdx.x & 63;
    if(lane == 0){ r1[w] = s1; r2[w] = s2; }
    __syncthreads();
    if(threadIdx.x == 0){
        atomicAdd(&st[g*2+0], r1[0]+r1[1]+r1[2]+r1[3]);
        atomicAdd(&st[g*2+1], r2[0]+r2[1]+r2[2]+r2[3]);
    }
}

// ---------------------------------------------------------------- GroupNorm apply + transpose
// grid = 32 groups x 32 t-tiles = 1024. Read Y^T [d][t] coalesced, normalize,
// LDS transpose, write ynb [t][h*64+d] coalesced (gemm_out A layout).
__global__ __launch_bounds__(256)
void gn_norm(const float* __restrict__ Y0, const float* __restrict__ Y1,
             const float* __restrict__ st,
             const float* __restrict__ gw, const float* __restrict__ gb,
             unsigned short* __restrict__ Out){
    __shared__ unsigned short T[64*72];
    const int g = blockIdx.x >> 5;
    if(g >= 32) return;
    const int t0 = (blockIdx.x & 31) * 64;
    const int h = g & 15, b = g >> 4;
    const float mean = st[g*2+0] * (1.0f/131072.0f);
    const float var  = st[g*2+1] * (1.0f/131072.0f) - mean*mean;
    const float inv  = rsqrtf(var + 1e-5f);
    const int tid = threadIdx.x;
    const bool hi = (t0 >= 1024);
    #pragma unroll
    for(int kk=0;kk<4;kk++){
        const int f4 = kk*256 + tid;
        const int d = f4 >> 4;
        const int t4l = f4 & 15;
        float4 v = ((const float4*)Y0)[(size_t)(g*64 + d)*512 + (t0>>2) + t4l];
        if(hi){
            float4 u = ((const float4*)Y1)[(size_t)(g*64 + d)*256 + ((t0-1024)>>2) + t4l];
            v.x += u.x; v.y += u.y; v.z += u.z; v.w += u.w;
        }
        const int c = h*64 + d;
        const float sc = inv * gw[c];
        const float bs = gb[c] - mean*sc;
        const int tl = t4l*4;
        T[(tl+0)*72 + d] = f2bf(v.x*sc + bs);
        T[(tl+1)*72 + d] = f2bf(v.y*sc + bs);
        T[(tl+2)*72 + d] = f2bf(v.z*sc + bs);
        T[(tl+3)*72 + d] = f2bf(v.w*sc + bs);
    }
    __syncthreads();
    #pragma unroll
    for(int it=0; it<2; it++){
        const int idx = it*256 + tid;
        const int tl = idx >> 3, segp = idx & 7;
        bf16x8 vrow = *(const bf16x8*)&T[tl*72 + segp*8];
        *(bf16x8*)&Out[((size_t)(b*2048 + t0 + tl))*1024 + h*64 + segp*8] = vrow;
    }
}

// ---------------------------------------------------------------- output GEMM
__global__ __launch_bounds__(256, 3)
void gemm_out(const unsigned short* __restrict__ A,
              const unsigned short* __restrict__ Bw,
              float* __restrict__ O)
{
    __shared__ unsigned short As[128*32];
    __shared__ unsigned short Bs[64*32];
    const int tid = threadIdx.x;
    const int w = tid >> 6, lane = tid & 63, q = lane >> 4, cl = lane & 15;
    const int i0 = blockIdx.x * 128, n0 = blockIdx.y * 64;
    const int wm = (w & 1) * 64, wn = (w >> 1) * 32;

    floatx4 acc[4][2];
    #pragma unroll
    for(int a=0;a<4;a++)
        #pragma unroll
        for(int b=0;b<2;b++) acc[a][b] = (floatx4)(0.0f);

    const int srow = lane >> 2;
    const int soff = (lane & 3) * 16;

    for(int k0 = 0; k0 < 1024; k0 += 32){
        __syncthreads();
        #pragma unroll
        for(int t=0;t<2;t++){
            const int ra = w*32 + t*16;
            gload_lds16((const char*)A + ((size_t)(i0 + ra + srow)*1024 + k0)*2 + soff,
                        (char*)&As[ra*32]);
        }
        gload_lds16((const char*)Bw + ((size_t)(n0 + w*16 + srow)*1024 + k0)*2 + soff,
                    (char*)&Bs[(w*16)*32]);
        __syncthreads();

        bf16x8 af[4], bfr[2];
        #pragma unroll
        for(int mi=0;mi<4;mi++) af[mi]  = *(const bf16x8*)&As[(wm + mi*16 + cl)*32 + q*8];
        #pragma unroll
        for(int ni=0;ni<2;ni++) bfr[ni] = *(const bf16x8*)&Bs[(wn + ni*16 + cl)*32 + q*8];
        #pragma unroll
        for(int mi=0;mi<4;mi++)
            #pragma unroll
            for(int ni=0;ni<2;ni++)
                acc[mi][ni] = __builtin_amdgcn_mfma_f32_16x16x32_bf16(af[mi], bfr[ni], acc[mi][ni], 0, 0, 0);
    }

    #pragma unroll
    for(int mi=0;mi<4;mi++)
        #pragma unroll
        for(int ni=0;ni<2;ni++){
            const int gi = i0 + wm + mi*16 + q*4;
            const int gn = n0 + wn + ni*16 + cl;
            #pragma unroll
            for(int r=0;r<4;r++) O[(size_t)(gi + r)*1024 + gn] = acc[mi][ni][r];
        }
}

// ---------------------------------------------------------------- launch
extern "C" void kernel_launch(void* const* d_in, const int* in_sizes, int n_in,
                              void* d_out, int out_size, void* d_ws, size_t ws_size,
                              hipStream_t stream){
    const float* x  = (const float*)d_in[0];
    const float* Wq = (const float*)d_in[1];
    const float* Wk = (const float*)d_in[2];
    const float* Wv = (const float*)d_in[3];
    const float* Wo = (const float*)d_in[4];
    const float* gw = (const float*)d_in[5];
    const float* gb = (const float*)d_in[6];

    char* ws = (char*)d_ws;
    unsigned short* xb  = (unsigned short*)(ws + ((size_t) 0<<20));
    unsigned short* wqb = (unsigned short*)(ws + ((size_t) 8<<20));
    unsigned short* wkb = (unsigned short*)(ws + ((size_t)10<<20));
    unsigned short* wvb = (unsigned short*)(ws + ((size_t)12<<20));
    unsigned short* wob = (unsigned short*)(ws + ((size_t)14<<20));
    unsigned short* qb  = (unsigned short*)(ws + ((size_t)16<<20));
    unsigned short* kb  = (unsigned short*)(ws + ((size_t)24<<20));
    unsigned short* vtb = (unsigned short*)(ws + ((size_t)32<<20));
    float*          y0  = (float*)         (ws + ((size_t)40<<20));
    unsigned short* ynb = (unsigned short*)(ws + ((size_t)56<<20));
    float*          y1  = (float*)         (ws + ((size_t) 0<<20));   // over xb
    float*          st  = (float*)         (ws + ((size_t)64<<20));   // 128 floats

    cvt_all<<<8192, 256, 0, stream>>>(x, Wq, Wk, Wv, Wo, xb, wqb, wkb, wvb, wob, st);

    gemm_qkv<<<dim3(32,24,1), 256, 0, stream>>>(xb, wqb, wkb, wvb, qb, kb, vtb);

    retention<<<dim3(16,32,1), 256, 0, stream>>>(qb, kb, vtb, y0, y1);

    gn_stats<<<256, 256, 0, stream>>>(y0, y1, st);
    gn_norm<<<1024, 256, 0, stream>>>(y0, y1, st, gw, gb, ynb);

    gemm_out<<<dim3(32,16,1), 256, 0, stream>>>(ynb, wob, (float*)d_out);
}